// Round 1
// baseline (6184.565 us; speedup 1.0000x reference)
//
#include <hip/hip_runtime.h>

#define BB 8
#define CH 256
#define C8 32
#define NP 4096   // 64*64

// -------------------- K1: q/k/v projections (1x1 convs as GEMM) -------------
__global__ __launch_bounds__(256) void qkv_kernel(
    const float* __restrict__ x,
    const float* __restrict__ wq, const float* __restrict__ bq,
    const float* __restrict__ wk, const float* __restrict__ bk,
    const float* __restrict__ wv, const float* __restrict__ bv,
    float* __restrict__ qo, float* __restrict__ ko, float* __restrict__ vo)
{
    int b  = blockIdx.z;
    int rg = blockIdx.y;          // 0..9 -> 320 output rows total
    int n0 = blockIdx.x * 128;
    int tid = threadIdx.x;
    int ty = tid >> 5, tx = tid & 31;

    __shared__ float Ws[32][33];
    __shared__ float Xs[32][128];

    int r_global = rg * 32;
    const float* Wbase; const float* bias; float* obase; int wrow0;
    if (r_global < 32)      { Wbase = wq; bias = bq; obase = qo + (size_t)b*C8*NP; wrow0 = 0; }
    else if (r_global < 64) { Wbase = wk; bias = bk; obase = ko + (size_t)b*C8*NP; wrow0 = 0; }
    else                    { Wbase = wv; bias = bv; obase = vo + (size_t)b*CH*NP; wrow0 = r_global - 64; }

    float acc[4][4] = {};

    for (int c0 = 0; c0 < CH; c0 += 32) {
        for (int e = tid; e < 32*32; e += 256) {
            int r = e >> 5, cc = e & 31;
            Ws[r][cc] = Wbase[(size_t)(wrow0 + r)*CH + c0 + cc];
        }
        for (int e = tid; e < 32*128; e += 256) {
            int cc = e >> 7, nn = e & 127;
            Xs[cc][nn] = x[(size_t)b*CH*NP + (size_t)(c0+cc)*NP + n0 + nn];
        }
        __syncthreads();
        #pragma unroll
        for (int cc = 0; cc < 32; ++cc) {
            float a[4], xv[4];
            #pragma unroll
            for (int i = 0; i < 4; ++i) a[i] = Ws[ty + 8*i][cc];
            #pragma unroll
            for (int j = 0; j < 4; ++j) xv[j] = Xs[cc][tx + 32*j];
            #pragma unroll
            for (int i = 0; i < 4; ++i)
                #pragma unroll
                for (int j = 0; j < 4; ++j)
                    acc[i][j] += a[i]*xv[j];
        }
        __syncthreads();
    }
    #pragma unroll
    for (int i = 0; i < 4; ++i) {
        int orow = wrow0 + ty + 8*i;
        float bb = bias[orow];
        #pragma unroll
        for (int j = 0; j < 4; ++j)
            obase[(size_t)orow*NP + n0 + tx + 32*j] = acc[i][j] + bb;
    }
}

// -------------------- K2: CAM energy  E[b,r,c] = sum_n x[r,n]x[c,n] ---------
__global__ __launch_bounds__(256) void cam_energy(
    const float* __restrict__ x, float* __restrict__ attnc)
{
    int b  = blockIdx.z;
    int r0 = blockIdx.y * 16;
    int c0 = blockIdx.x * 16;
    int tid = threadIdx.x;
    int tr = tid >> 4, tc = tid & 15;

    __shared__ float As[16][132];
    __shared__ float Bs[16][132];

    float acc = 0.f;
    for (int n0 = 0; n0 < NP; n0 += 128) {
        for (int e = tid; e < 16*128; e += 256) {
            int r = e >> 7, nn = e & 127;
            As[r][nn] = x[(size_t)b*CH*NP + (size_t)(r0+r)*NP + n0 + nn];
            Bs[r][nn] = x[(size_t)b*CH*NP + (size_t)(c0+r)*NP + n0 + nn];
        }
        __syncthreads();
        #pragma unroll
        for (int nn = 0; nn < 128; ++nn)
            acc += As[tr][nn] * Bs[tc][nn];
        __syncthreads();
    }
    attnc[(size_t)b*CH*CH + (size_t)(r0+tr)*CH + c0 + tc] = acc;
}

// -------------------- K3: row softmax on [256] rows -------------------------
__global__ __launch_bounds__(256) void cam_softmax(float* __restrict__ attnc)
{
    int b = blockIdx.y, r = blockIdx.x;
    int tid = threadIdx.x;
    int lane = tid & 63, wid = tid >> 6;
    float* row = attnc + (size_t)b*CH*CH + (size_t)r*CH;
    float e = row[tid];

    __shared__ float redm[4], reds[4];
    float m = e;
    #pragma unroll
    for (int off = 32; off >= 1; off >>= 1) m = fmaxf(m, __shfl_xor(m, off));
    if (lane == 0) redm[wid] = m;
    __syncthreads();
    m = fmaxf(fmaxf(redm[0], redm[1]), fmaxf(redm[2], redm[3]));

    float p = __expf(e - m);
    float s = p;
    #pragma unroll
    for (int off = 32; off >= 1; off >>= 1) s += __shfl_xor(s, off);
    if (lane == 0) reds[wid] = s;
    __syncthreads();
    s = reds[0] + reds[1] + reds[2] + reds[3];
    row[tid] = p / s;
}

// -------------------- K4: out = gamma*(A@X) + x -----------------------------
__global__ __launch_bounds__(256) void cam_apply(
    const float* __restrict__ x, const float* __restrict__ attnc,
    const float* __restrict__ gamma, float* __restrict__ out)
{
    int b  = blockIdx.z;
    int c0 = blockIdx.y * 32;
    int n0 = blockIdx.x * 128;
    int tid = threadIdx.x;
    int ty = tid >> 5, tx = tid & 31;

    __shared__ float At[32][33];
    __shared__ float Xs[32][128];

    float acc[4][4] = {};
    for (int d0 = 0; d0 < CH; d0 += 32) {
        for (int e = tid; e < 1024; e += 256) {
            int cl = e >> 5, dd = e & 31;
            At[cl][dd] = attnc[(size_t)b*CH*CH + (size_t)(c0+cl)*CH + d0 + dd];
        }
        for (int e = tid; e < 4096; e += 256) {
            int dd = e >> 7, nn = e & 127;
            Xs[dd][nn] = x[(size_t)b*CH*NP + (size_t)(d0+dd)*NP + n0 + nn];
        }
        __syncthreads();
        #pragma unroll
        for (int dd = 0; dd < 32; ++dd) {
            float a[4], xv[4];
            #pragma unroll
            for (int i = 0; i < 4; ++i) a[i] = At[ty + 8*i][dd];
            #pragma unroll
            for (int j = 0; j < 4; ++j) xv[j] = Xs[dd][tx + 32*j];
            #pragma unroll
            for (int i = 0; i < 4; ++i)
                #pragma unroll
                for (int j = 0; j < 4; ++j)
                    acc[i][j] += a[i]*xv[j];
        }
        __syncthreads();
    }
    float g = gamma[0];
    #pragma unroll
    for (int i = 0; i < 4; ++i) {
        #pragma unroll
        for (int j = 0; j < 4; ++j) {
            size_t idx = (size_t)b*CH*NP + (size_t)(c0+ty+8*i)*NP + n0 + tx + 32*j;
            out[idx] = g*acc[i][j] + x[idx];
        }
    }
}

// -------------------- K5: PAM pass 1 — per-row softmax stats (m, 1/l) -------
__global__ __launch_bounds__(256) void pam_pass1(
    const float* __restrict__ qw, const float* __restrict__ kw,
    float* __restrict__ mbuf, float* __restrict__ lbuf)
{
    int b  = blockIdx.y;
    int i0 = blockIdx.x * 32;
    int tid = threadIdx.x;
    int lane = tid & 63, wid = tid >> 6;

    __shared__ float qs[32][32];      // [d][ii], broadcast reads
    for (int e = tid; e < 1024; e += 256) {
        int d = e >> 5, ii = e & 31;
        qs[d][ii] = qw[(size_t)b*C8*NP + (size_t)d*NP + i0 + ii];
    }
    __syncthreads();

    float mloc[32], lloc[32];
    #pragma unroll
    for (int ii = 0; ii < 32; ++ii) { mloc[ii] = -1e30f; lloc[ii] = 0.f; }

    for (int j0 = 0; j0 < NP; j0 += 256) {
        int j = j0 + tid;
        float kreg[32];
        #pragma unroll
        for (int d = 0; d < 32; ++d)
            kreg[d] = kw[(size_t)b*C8*NP + (size_t)d*NP + j];
        #pragma unroll
        for (int ii = 0; ii < 32; ++ii) {
            float s = 0.f;
            #pragma unroll
            for (int d = 0; d < 32; ++d) s += qs[d][ii]*kreg[d];
            float mo = mloc[ii];
            float mn = fmaxf(mo, s);
            lloc[ii] = lloc[ii]*__expf(mo - mn) + __expf(s - mn);
            mloc[ii] = mn;
        }
    }

    __shared__ float redm[4][32], redl[4][32];
    #pragma unroll
    for (int ii = 0; ii < 32; ++ii) {
        float m = mloc[ii], l = lloc[ii];
        #pragma unroll
        for (int off = 1; off < 64; off <<= 1) {
            float mo = __shfl_xor(m, off);
            float lo = __shfl_xor(l, off);
            float mn = fmaxf(m, mo);
            l = l*__expf(m - mn) + lo*__expf(mo - mn);
            m = mn;
        }
        if (lane == 0) { redm[wid][ii] = m; redl[wid][ii] = l; }
    }
    __syncthreads();
    if (tid < 32) {
        int ii = tid;
        float m = redm[0][ii], l = redl[0][ii];
        #pragma unroll
        for (int w = 1; w < 4; ++w) {
            float mo = redm[w][ii], lo = redl[w][ii];
            float mn = fmaxf(m, mo);
            l = l*__expf(m - mn) + lo*__expf(mo - mn);
            m = mn;
        }
        mbuf[(size_t)b*NP + i0 + ii] = m;
        lbuf[(size_t)b*NP + i0 + ii] = 1.0f / l;
    }
}

// -------------------- K6: PAM pass 2 — out += P @ V^T -----------------------
__global__ __launch_bounds__(256) void pam_pass2(
    const float* __restrict__ qw, const float* __restrict__ kw,
    const float* __restrict__ vw, const float* __restrict__ mbuf,
    const float* __restrict__ lbuf, float* __restrict__ out)
{
    int b  = blockIdx.y;
    int i0 = blockIdx.x * 64;
    int tid = threadIdx.x;
    int ty = tid >> 3;   // 0..31 (c groups, stride 32)
    int tx = tid & 7;    // 0..7  (i groups, stride 8)

    __shared__ float qs[32][64];      // [d][ii]
    __shared__ float ks[32][33];      // [d][jj]
    __shared__ float ps[64][36];      // [ii][jj]
    __shared__ float vs[256][36];     // [c][jj]
    __shared__ float msh[64], lsh[64];

    for (int e = tid; e < 32*64; e += 256) {
        int d = e >> 6, ii = e & 63;
        qs[d][ii] = qw[(size_t)b*C8*NP + (size_t)d*NP + i0 + ii];
    }
    if (tid < 64) {
        msh[tid] = mbuf[(size_t)b*NP + i0 + tid];
        lsh[tid] = lbuf[(size_t)b*NP + i0 + tid];
    }
    float acc[8][8] = {};
    __syncthreads();

    for (int j0 = 0; j0 < NP; j0 += 32) {
        for (int e = tid; e < 32*32; e += 256) {
            int d = e >> 5, jj = e & 31;
            ks[d][jj] = kw[(size_t)b*C8*NP + (size_t)d*NP + j0 + jj];
        }
        for (int e = tid; e < 256*32; e += 256) {
            int c = e >> 5, jj = e & 31;
            vs[c][jj] = vw[(size_t)b*CH*NP + (size_t)c*NP + j0 + jj];
        }
        __syncthreads();
        {
            int jj  = tid & 31;
            int iiB = (tid >> 5) * 8;
            #pragma unroll
            for (int u = 0; u < 8; ++u) {
                int ii = iiB + u;
                float s = 0.f;
                #pragma unroll
                for (int d = 0; d < 32; ++d) s += ks[d][jj]*qs[d][ii];
                ps[ii][jj] = __expf(s - msh[ii]) * lsh[ii];
            }
        }
        __syncthreads();
        #pragma unroll
        for (int jq = 0; jq < 32; jq += 4) {
            float4 pp[8];
            #pragma unroll
            for (int im = 0; im < 8; ++im)
                pp[im] = *(const float4*)&ps[tx + 8*im][jq];
            #pragma unroll
            for (int cm = 0; cm < 8; ++cm) {
                float4 vv = *(const float4*)&vs[ty + 32*cm][jq];
                #pragma unroll
                for (int im = 0; im < 8; ++im)
                    acc[cm][im] += vv.x*pp[im].x + vv.y*pp[im].y
                                 + vv.z*pp[im].z + vv.w*pp[im].w;
            }
        }
        __syncthreads();
    }

    #pragma unroll
    for (int cm = 0; cm < 8; ++cm) {
        int c = ty + 32*cm;
        #pragma unroll
        for (int im = 0; im < 8; ++im) {
            size_t idx = (size_t)b*CH*NP + (size_t)c*NP + i0 + tx + 8*im;
            out[idx] += acc[cm][im];
        }
    }
}

// ---------------------------------------------------------------------------
extern "C" void kernel_launch(void* const* d_in, const int* in_sizes, int n_in,
                              void* d_out, int out_size, void* d_ws, size_t ws_size,
                              hipStream_t stream)
{
    const float* x     = (const float*)d_in[0];
    const float* gamma = (const float*)d_in[1];
    const float* wq    = (const float*)d_in[2];
    const float* bq    = (const float*)d_in[3];
    const float* wk    = (const float*)d_in[4];
    const float* bk    = (const float*)d_in[5];
    const float* wv    = (const float*)d_in[6];
    const float* bv    = (const float*)d_in[7];
    float* out = (float*)d_out;

    float* ws    = (float*)d_ws;
    float* qw    = ws;                              // B*32*N   = 1,048,576
    float* kw    = qw   + (size_t)BB*C8*NP;         // B*32*N
    float* vw    = kw   + (size_t)BB*C8*NP;         // B*256*N  = 8,388,608
    float* attnc = vw   + (size_t)BB*CH*NP;         // B*256*256
    float* mbuf  = attnc+ (size_t)BB*CH*CH;         // B*N
    float* lbuf  = mbuf + (size_t)BB*NP;            // B*N

    qkv_kernel <<<dim3(32, 10, BB), 256, 0, stream>>>(x, wq, bq, wk, bk, wv, bv, qw, kw, vw);
    cam_energy <<<dim3(16, 16, BB), 256, 0, stream>>>(x, attnc);
    cam_softmax<<<dim3(CH, BB),     256, 0, stream>>>(attnc);
    cam_apply  <<<dim3(32, 8, BB),  256, 0, stream>>>(x, attnc, gamma, out);
    pam_pass1  <<<dim3(128, BB),    256, 0, stream>>>(qw, kw, mbuf, lbuf);
    pam_pass2  <<<dim3(64, BB),     256, 0, stream>>>(qw, kw, vw, mbuf, lbuf, out);
}

// Round 2
// 648.852 us; speedup vs baseline: 9.5316x; 9.5316x over previous
//
#include <hip/hip_runtime.h>
#include <hip/hip_bf16.h>

#define BB 8
#define CH 256
#define C8 32
#define NP 4096   // 64*64

typedef __attribute__((ext_vector_type(8))) short bf16x8;
typedef __attribute__((ext_vector_type(4))) float f32x4;

__device__ __forceinline__ void async_copy16(const void* src, void* dst_lds) {
    __builtin_amdgcn_global_load_lds(
        (const __attribute__((address_space(1))) unsigned int*)src,
        (__attribute__((address_space(3))) unsigned int*)dst_lds, 16, 0, 0);
}

__device__ __forceinline__ unsigned long long pack4bf(float a, float b, float c, float d) {
    union { __hip_bfloat16 h[4]; unsigned long long u; } p;
    p.h[0] = __float2bfloat16(a);
    p.h[1] = __float2bfloat16(b);
    p.h[2] = __float2bfloat16(c);
    p.h[3] = __float2bfloat16(d);
    return p.u;
}

// -------------------- K1: q/k/v projections -> bf16 (q,k transposed) --------
__global__ __launch_bounds__(256) void qkv_kernel(
    const float* __restrict__ x,
    const float* __restrict__ wq, const float* __restrict__ bq,
    const float* __restrict__ wk, const float* __restrict__ bk,
    const float* __restrict__ wv, const float* __restrict__ bv,
    __hip_bfloat16* __restrict__ qt,   // [B][N][32]
    __hip_bfloat16* __restrict__ kt,   // [B][N][32]
    __hip_bfloat16* __restrict__ vb)   // [B][C][N]
{
    int b  = blockIdx.z;
    int rg = blockIdx.y;          // 0..9 -> 320 output rows total
    int n0 = blockIdx.x * 128;
    int tid = threadIdx.x;
    int ty = tid >> 5, tx = tid & 31;

    __shared__ float Ws[32][33];
    __shared__ float Xs[32][128];

    int r_global = rg * 32;
    const float* Wbase; const float* bias; int wrow0; int kind;
    if (r_global < 32)      { Wbase = wq; bias = bq; wrow0 = 0; kind = 0; }
    else if (r_global < 64) { Wbase = wk; bias = bk; wrow0 = 0; kind = 1; }
    else                    { Wbase = wv; bias = bv; wrow0 = r_global - 64; kind = 2; }

    float acc[4][4] = {};

    for (int c0 = 0; c0 < CH; c0 += 32) {
        for (int e = tid; e < 32*32; e += 256) {
            int r = e >> 5, cc = e & 31;
            Ws[r][cc] = Wbase[(size_t)(wrow0 + r)*CH + c0 + cc];
        }
        for (int e = tid; e < 32*128; e += 256) {
            int cc = e >> 7, nn = e & 127;
            Xs[cc][nn] = x[(size_t)b*CH*NP + (size_t)(c0+cc)*NP + n0 + nn];
        }
        __syncthreads();
        #pragma unroll
        for (int cc = 0; cc < 32; ++cc) {
            float a[4], xv[4];
            #pragma unroll
            for (int i = 0; i < 4; ++i) a[i] = Ws[ty + 8*i][cc];
            #pragma unroll
            for (int j = 0; j < 4; ++j) xv[j] = Xs[cc][tx + 32*j];
            #pragma unroll
            for (int i = 0; i < 4; ++i)
                #pragma unroll
                for (int j = 0; j < 4; ++j)
                    acc[i][j] += a[i]*xv[j];
        }
        __syncthreads();
    }
    #pragma unroll
    for (int i = 0; i < 4; ++i) {
        int orow = wrow0 + ty + 8*i;
        float bb = bias[orow];
        #pragma unroll
        for (int j = 0; j < 4; ++j) {
            float val = acc[i][j] + bb;
            int n = n0 + tx + 32*j;
            if (kind == 0)
                qt[((size_t)b*NP + n)*C8 + orow] = __float2bfloat16(val);
            else if (kind == 1)
                kt[((size_t)b*NP + n)*C8 + orow] = __float2bfloat16(val);
            else
                vb[(size_t)b*CH*NP + (size_t)orow*NP + n] = __float2bfloat16(val);
        }
    }
}

// -------------------- K2: CAM energy  E[b,r,c] = sum_n x[r,n]x[c,n] ---------
__global__ __launch_bounds__(256) void cam_energy(
    const float* __restrict__ x, float* __restrict__ attnc)
{
    int b  = blockIdx.z;
    int r0 = blockIdx.y * 16;
    int c0 = blockIdx.x * 16;
    int tid = threadIdx.x;
    int tr = tid >> 4, tc = tid & 15;

    __shared__ float As[16][132];
    __shared__ float Bs[16][132];

    float acc = 0.f;
    for (int n0 = 0; n0 < NP; n0 += 128) {
        for (int e = tid; e < 16*128; e += 256) {
            int r = e >> 7, nn = e & 127;
            As[r][nn] = x[(size_t)b*CH*NP + (size_t)(r0+r)*NP + n0 + nn];
            Bs[r][nn] = x[(size_t)b*CH*NP + (size_t)(c0+r)*NP + n0 + nn];
        }
        __syncthreads();
        #pragma unroll
        for (int nn = 0; nn < 128; ++nn)
            acc += As[tr][nn] * Bs[tc][nn];
        __syncthreads();
    }
    attnc[(size_t)b*CH*CH + (size_t)(r0+tr)*CH + c0 + tc] = acc;
}

// -------------------- K3: row softmax on [256] rows -------------------------
__global__ __launch_bounds__(256) void cam_softmax(float* __restrict__ attnc)
{
    int b = blockIdx.y, r = blockIdx.x;
    int tid = threadIdx.x;
    int lane = tid & 63, wid = tid >> 6;
    float* row = attnc + (size_t)b*CH*CH + (size_t)r*CH;
    float e = row[tid];

    __shared__ float redm[4], reds[4];
    float m = e;
    #pragma unroll
    for (int off = 32; off >= 1; off >>= 1) m = fmaxf(m, __shfl_xor(m, off));
    if (lane == 0) redm[wid] = m;
    __syncthreads();
    m = fmaxf(fmaxf(redm[0], redm[1]), fmaxf(redm[2], redm[3]));

    float p = __expf(e - m);
    float s = p;
    #pragma unroll
    for (int off = 32; off >= 1; off >>= 1) s += __shfl_xor(s, off);
    if (lane == 0) reds[wid] = s;
    __syncthreads();
    s = reds[0] + reds[1] + reds[2] + reds[3];
    row[tid] = p / s;
}

// -------------------- K4: out = gamma*(A@X) + x -----------------------------
__global__ __launch_bounds__(256) void cam_apply(
    const float* __restrict__ x, const float* __restrict__ attnc,
    const float* __restrict__ gamma, float* __restrict__ out)
{
    int b  = blockIdx.z;
    int c0 = blockIdx.y * 32;
    int n0 = blockIdx.x * 128;
    int tid = threadIdx.x;
    int ty = tid >> 5, tx = tid & 31;

    __shared__ float At[32][33];
    __shared__ float Xs[32][128];

    float acc[4][4] = {};
    for (int d0 = 0; d0 < CH; d0 += 32) {
        for (int e = tid; e < 1024; e += 256) {
            int cl = e >> 5, dd = e & 31;
            At[cl][dd] = attnc[(size_t)b*CH*CH + (size_t)(c0+cl)*CH + d0 + dd];
        }
        for (int e = tid; e < 4096; e += 256) {
            int dd = e >> 7, nn = e & 127;
            Xs[dd][nn] = x[(size_t)b*CH*NP + (size_t)(d0+dd)*NP + n0 + nn];
        }
        __syncthreads();
        #pragma unroll
        for (int dd = 0; dd < 32; ++dd) {
            float a[4], xv[4];
            #pragma unroll
            for (int i = 0; i < 4; ++i) a[i] = At[ty + 8*i][dd];
            #pragma unroll
            for (int j = 0; j < 4; ++j) xv[j] = Xs[dd][tx + 32*j];
            #pragma unroll
            for (int i = 0; i < 4; ++i)
                #pragma unroll
                for (int j = 0; j < 4; ++j)
                    acc[i][j] += a[i]*xv[j];
        }
        __syncthreads();
    }
    float g = gamma[0];
    #pragma unroll
    for (int i = 0; i < 4; ++i) {
        #pragma unroll
        for (int j = 0; j < 4; ++j) {
            size_t idx = (size_t)b*CH*NP + (size_t)(c0+ty+8*i)*NP + n0 + tx + 32*j;
            out[idx] = g*acc[i][j] + x[idx];
        }
    }
}

// -------------------- K5: PAM flash (MFMA bf16, unnormalized exp) -----------
// Block: 4 waves, i-tile = 64 rows, j-tile = 64, C = 256 output channels.
// out[b][c][i] += (sum_j exp(s_ij) * v[c][j]) / (sum_j exp(s_ij))
__global__ __launch_bounds__(256) void pam_flash(
    const __hip_bfloat16* __restrict__ qg,   // [B][N][32]
    const __hip_bfloat16* __restrict__ kg,   // [B][N][32]
    const __hip_bfloat16* __restrict__ vg,   // [B][C][N]
    float* __restrict__ out)
{
    const int b  = blockIdx.y;
    const int i0 = blockIdx.x * 64;
    const int tid = threadIdx.x;
    const int w  = tid >> 6;          // wave 0..3
    const int l  = tid & 63;
    const int g  = l >> 4;            // lane group 0..3
    const int li = l & 15;

    __shared__ __align__(16) __hip_bfloat16 qt[64*32];     // [i][d]    4KB
    __shared__ __align__(16) __hip_bfloat16 kt[64*32];     // [j][d]    4KB
    __shared__ __align__(16) __hip_bfloat16 vs[256*64];    // [c][j] sw 32KB
    __shared__ __align__(16) __hip_bfloat16 ps[64*72];     // [i][j]+pad 9KB
    __shared__ float lsh[4][64];

    // ---- stage Q tile (contiguous 4KB), one instr per wave ----
    {
        const char* src = (const char*)(qg + ((size_t)b*NP + i0)*C8) + (size_t)w*1024 + l*16;
        async_copy16(src, (char*)qt + w*1024);
    }
    __syncthreads();

    // Q B-frags: B[d][i]; lane: col i = t*16+li, k d = g*8..g*8+7
    bf16x8 qf[4];
    #pragma unroll
    for (int t = 0; t < 4; ++t)
        qf[t] = *(const bf16x8*)((const char*)qt + (t*16 + li)*64 + g*16);

    f32x4 acc[4][4];   // [i-frag t][c-frag ct]
    #pragma unroll
    for (int t = 0; t < 4; ++t)
        #pragma unroll
        for (int ct = 0; ct < 4; ++ct)
            acc[t][ct] = (f32x4){0.f, 0.f, 0.f, 0.f};
    float lacc[4] = {0.f, 0.f, 0.f, 0.f};

    for (int j0 = 0; j0 < NP; j0 += 64) {
        // ---- stage K tile [64][32] (contiguous 4KB) ----
        {
            const char* src = (const char*)(kg + ((size_t)b*NP + j0)*C8) + (size_t)w*1024 + l*16;
            async_copy16(src, (char*)kt + w*1024);
        }
        // ---- stage V tile [256 c][64 j], XOR-swizzled 16B slots ----
        // linear slot S16 = w*512 + it*64 + l holds (c = S16>>3, jb' = S16&7),
        // whose DATA is jb = jb' ^ (c&7)  (so reads can use byte ^= (c&7)<<4)
        #pragma unroll
        for (int it = 0; it < 8; ++it) {
            int S16 = w*512 + it*64 + l;
            int c   = S16 >> 3;
            int jb  = (S16 & 7) ^ (c & 7);
            const char* src = (const char*)vg +
                ((size_t)(b*CH + c)*NP + j0 + jb*8)*2;
            async_copy16(src, (char*)vs + w*8192 + it*1024);
        }
        __syncthreads();

        // ---- QK^T: wave w computes S^T rows j in [w*16, w*16+16) ----
        bf16x8 ka = *(const bf16x8*)((const char*)kt + (w*16 + li)*64 + g*16);
        f32x4 st[4];
        #pragma unroll
        for (int t = 0; t < 4; ++t) {
            f32x4 z = (f32x4){0.f, 0.f, 0.f, 0.f};
            st[t] = __builtin_amdgcn_mfma_f32_16x16x32_bf16(ka, qf[t], z, 0, 0, 0);
        }
        // ---- exp (unnormalized), l-accumulate, write P[i][j] bf16 ----
        #pragma unroll
        for (int t = 0; t < 4; ++t) {
            float p0 = __expf(st[t][0]);
            float p1 = __expf(st[t][1]);
            float p2 = __expf(st[t][2]);
            float p3 = __expf(st[t][3]);
            lacc[t] += (p0 + p1) + (p2 + p3);
            // D layout: row j = w*16 + g*4 + r, col i = t*16 + li
            *(unsigned long long*)((char*)ps + (t*16 + li)*144 + (w*16 + g*4)*2)
                = pack4bf(p0, p1, p2, p3);
        }
        __syncthreads();

        // ---- PV: wave w owns c in [w*64, w*64+64) ----
        #pragma unroll
        for (int ks = 0; ks < 2; ++ks) {
            bf16x8 ap[4];
            #pragma unroll
            for (int t = 0; t < 4; ++t)
                ap[t] = *(const bf16x8*)((const char*)ps + (t*16 + li)*144 + ks*64 + g*16);
            #pragma unroll
            for (int ct = 0; ct < 4; ++ct) {
                int c = w*64 + ct*16 + li;
                bf16x8 bv = *(const bf16x8*)((const char*)vs + c*128 +
                                (((ks*4 + g) ^ (c & 7)) << 4));
                #pragma unroll
                for (int t = 0; t < 4; ++t)
                    acc[t][ct] = __builtin_amdgcn_mfma_f32_16x16x32_bf16(ap[t], bv, acc[t][ct], 0, 0, 0);
            }
        }
        __syncthreads();
    }

    // ---- reduce l across lane groups (g) then waves ----
    #pragma unroll
    for (int t = 0; t < 4; ++t) {
        float v = lacc[t];
        v += __shfl_xor(v, 16);
        v += __shfl_xor(v, 32);
        lacc[t] = v;
    }
    if (g == 0) {
        #pragma unroll
        for (int t = 0; t < 4; ++t) lsh[w][t*16 + li] = lacc[t];
    }
    __syncthreads();

    // ---- epilogue: out[b][c][i] += acc / l ----
    #pragma unroll
    for (int t = 0; t < 4; ++t) {
        float linv[4];
        #pragma unroll
        for (int r = 0; r < 4; ++r) {
            int il = t*16 + g*4 + r;
            linv[r] = 1.0f / (lsh[0][il] + lsh[1][il] + lsh[2][il] + lsh[3][il]);
        }
        #pragma unroll
        for (int ct = 0; ct < 4; ++ct) {
            int c = w*64 + ct*16 + li;
            size_t base = ((size_t)b*CH + c)*NP + i0 + t*16 + g*4;
            float4 o = *(float4*)(out + base);
            o.x += acc[t][ct][0]*linv[0];
            o.y += acc[t][ct][1]*linv[1];
            o.z += acc[t][ct][2]*linv[2];
            o.w += acc[t][ct][3]*linv[3];
            *(float4*)(out + base) = o;
        }
    }
}

// ---------------------------------------------------------------------------
extern "C" void kernel_launch(void* const* d_in, const int* in_sizes, int n_in,
                              void* d_out, int out_size, void* d_ws, size_t ws_size,
                              hipStream_t stream)
{
    const float* x     = (const float*)d_in[0];
    const float* gamma = (const float*)d_in[1];
    const float* wq    = (const float*)d_in[2];
    const float* bq    = (const float*)d_in[3];
    const float* wk    = (const float*)d_in[4];
    const float* bk    = (const float*)d_in[5];
    const float* wv    = (const float*)d_in[6];
    const float* bv    = (const float*)d_in[7];
    float* out = (float*)d_out;

    __hip_bfloat16* qtb = (__hip_bfloat16*)d_ws;             // B*N*32
    __hip_bfloat16* ktb = qtb + (size_t)BB*NP*C8;            // B*N*32
    __hip_bfloat16* vbb = ktb + (size_t)BB*NP*C8;            // B*C*N
    float* attnc = (float*)(vbb + (size_t)BB*CH*NP);         // B*C*C

    qkv_kernel <<<dim3(32, 10, BB), 256, 0, stream>>>(x, wq, bq, wk, bk, wv, bv, qtb, ktb, vbb);
    cam_energy <<<dim3(16, 16, BB), 256, 0, stream>>>(x, attnc);
    cam_softmax<<<dim3(CH, BB),     256, 0, stream>>>(attnc);
    cam_apply  <<<dim3(32, 8, BB),  256, 0, stream>>>(x, attnc, gamma, out);
    pam_flash  <<<dim3(NP/64, BB),  256, 0, stream>>>(qtb, ktb, vbb, out);
}

// Round 3
// 243.401 us; speedup vs baseline: 25.4090x; 2.6658x over previous
//
#include <hip/hip_runtime.h>
#include <hip/hip_bf16.h>

#define BB 8
#define CH 256
#define C8 32
#define NP 4096   // 64*64

typedef __attribute__((ext_vector_type(8))) short bf16x8;
typedef __attribute__((ext_vector_type(4))) float f32x4;

#define MFMA16(a, b, c) __builtin_amdgcn_mfma_f32_16x16x32_bf16(a, b, c, 0, 0, 0)

__device__ __forceinline__ void async_copy16(const void* src, void* dst_lds) {
    __builtin_amdgcn_global_load_lds(
        (const __attribute__((address_space(1))) unsigned int*)src,
        (__attribute__((address_space(3))) unsigned int*)dst_lds, 16, 0, 0);
}

__device__ __forceinline__ unsigned long long pack4bf(float a, float b, float c, float d) {
    union { __hip_bfloat16 h[4]; unsigned long long u; } p;
    p.h[0] = __float2bfloat16(a);
    p.h[1] = __float2bfloat16(b);
    p.h[2] = __float2bfloat16(c);
    p.h[3] = __float2bfloat16(d);
    return p.u;
}

// Stage a [nrows][64] bf16 LDS panel (128B rows, XOR-swizzled: data k-chunk t
// of row r lives at slot t^(r&7)) from row-major bf16 global (stride rowStride
// elems) starting at column k0. Wave-uniform LDS dst + per-lane global src.
__device__ __forceinline__ void stage_panel64(
    const __hip_bfloat16* __restrict__ src, int rowStride, int k0,
    __hip_bfloat16* lds, int nrows, int w, int l)
{
    const int nslots = nrows * 8;
    for (int S0 = w*64; S0 < nslots; S0 += 256) {
        int S = S0 + l;
        int r = S >> 3, s = S & 7;
        int jb = s ^ (r & 7);
        async_copy16(src + (size_t)r*rowStride + k0 + jb*8,
                     (char*)lds + (size_t)S0*16);
    }
}

// Same panel layout but from fp32 global, converted through registers.
__device__ __forceinline__ void stage_panel64_f32(
    const float* __restrict__ src, int rowStride, int k0,
    __hip_bfloat16* lds, int nrows, int tid)
{
    const int nslots = nrows * 8;
    for (int S = tid; S < nslots; S += 256) {
        int r = S >> 3, s = S & 7;
        int jb = s ^ (r & 7);
        const float* p = src + (size_t)r*rowStride + k0 + jb*8;
        float4 a = *(const float4*)p;
        float4 b = *(const float4*)(p + 4);
        union { __hip_bfloat16 h[8]; bf16x8 v; } u;
        u.h[0] = __float2bfloat16(a.x); u.h[1] = __float2bfloat16(a.y);
        u.h[2] = __float2bfloat16(a.z); u.h[3] = __float2bfloat16(a.w);
        u.h[4] = __float2bfloat16(b.x); u.h[5] = __float2bfloat16(b.y);
        u.h[6] = __float2bfloat16(b.z); u.h[7] = __float2bfloat16(b.w);
        *(bf16x8*)((char*)lds + (size_t)S*16) = u.v;
    }
}

// Read one 8-bf16 fragment (row r, k-chunk t in 0..7) from a swizzled panel.
__device__ __forceinline__ bf16x8 frag64(const __hip_bfloat16* lds, int r, int t) {
    return *(const bf16x8*)((const char*)lds + r*128 + ((t ^ (r & 7)) << 4));
}

// -------------------- K0a: weights -> bf16 ----------------------------------
__global__ __launch_bounds__(256) void convert_w(
    const float* __restrict__ wq, const float* __restrict__ wk,
    const float* __restrict__ wv,
    __hip_bfloat16* __restrict__ wqkb, __hip_bfloat16* __restrict__ wvb)
{
    int id = blockIdx.x * 256 + threadIdx.x;
    if (id < 64*256) {
        float v = (id < 32*256) ? wq[id] : wk[id - 32*256];
        wqkb[id] = __float2bfloat16(v);
    } else {
        int j = id - 64*256;
        wvb[j] = __float2bfloat16(wv[j]);
    }
}

// -------------------- K0b: x -> xbT [B][N][C] bf16 (transpose) --------------
__global__ __launch_bounds__(256) void convert_T(
    const float* __restrict__ x, __hip_bfloat16* __restrict__ xbT)
{
    int b = blockIdx.z, c0 = blockIdx.y * 64, n0 = blockIdx.x * 64;
    __shared__ float t[64][65];
    int tid = threadIdx.x;
    int nn = tid & 63, ch = tid >> 6;
    const float* xp = x + (size_t)b*CH*NP + (size_t)c0*NP + n0;
    #pragma unroll
    for (int u = 0; u < 16; ++u)
        t[ch + u*4][nn] = xp[(size_t)(ch + u*4)*NP + nn];
    __syncthreads();
    int n = tid >> 2, seg = tid & 3;
    union { __hip_bfloat16 h[16]; bf16x8 v[2]; } u16;
    #pragma unroll
    for (int u = 0; u < 16; ++u)
        u16.h[u] = __float2bfloat16(t[seg*16 + u][n]);
    __hip_bfloat16* dst = xbT + ((size_t)b*NP + n0 + n)*CH + c0 + seg*16;
    *(bf16x8*)dst = u16.v[0];
    *(bf16x8*)(dst + 8) = u16.v[1];
}

// -------------------- K1: q,k projections (MFMA) ----------------------------
// D[n][o] = sum_d xbT[n][d] * wqk[o][d];  o<32 -> q, else k.  M=128,N=64,K=256
__global__ __launch_bounds__(256) void qk_kernel(
    const __hip_bfloat16* __restrict__ xbT, const __hip_bfloat16* __restrict__ wqkb,
    const float* __restrict__ bq, const float* __restrict__ bk,
    __hip_bfloat16* __restrict__ qt, __hip_bfloat16* __restrict__ kt)
{
    const int b = blockIdx.y, n0 = blockIdx.x * 128;
    const int tid = threadIdx.x;
    const int w = tid >> 6, l = tid & 63, g = l >> 4, li = l & 15;

    __shared__ __align__(16) __hip_bfloat16 Ap[128*64];   // xbT rows (n)
    __shared__ __align__(16) __hip_bfloat16 Bp[64*64];    // wqk rows (o)

    f32x4 acc[2][4];
    #pragma unroll
    for (int mf = 0; mf < 2; ++mf)
        #pragma unroll
        for (int nf = 0; nf < 4; ++nf) acc[mf][nf] = (f32x4){0.f,0.f,0.f,0.f};

    const __hip_bfloat16* asrc = xbT + ((size_t)b*NP + n0)*CH;
    for (int kt4 = 0; kt4 < 4; ++kt4) {
        stage_panel64(asrc, CH, kt4*64, Ap, 128, w, l);
        stage_panel64(wqkb, CH, kt4*64, Bp, 64, w, l);
        __syncthreads();
        #pragma unroll
        for (int ks = 0; ks < 2; ++ks) {
            bf16x8 af[2], bf[4];
            #pragma unroll
            for (int mf = 0; mf < 2; ++mf) af[mf] = frag64(Ap, w*32 + mf*16 + li, ks*4 + g);
            #pragma unroll
            for (int nf = 0; nf < 4; ++nf) bf[nf] = frag64(Bp, nf*16 + li, ks*4 + g);
            #pragma unroll
            for (int mf = 0; mf < 2; ++mf)
                #pragma unroll
                for (int nf = 0; nf < 4; ++nf)
                    acc[mf][nf] = MFMA16(af[mf], bf[nf], acc[mf][nf]);
        }
        __syncthreads();
    }
    #pragma unroll
    for (int mf = 0; mf < 2; ++mf)
        #pragma unroll
        for (int nf = 0; nf < 4; ++nf)
            #pragma unroll
            for (int q = 0; q < 4; ++q) {
                int n = n0 + w*32 + mf*16 + g*4 + q;
                int o = nf*16 + li;
                float bias = (o < 32) ? bq[o] : bk[o - 32];
                __hip_bfloat16* dst = (o < 32) ? qt : kt;
                dst[((size_t)b*NP + n)*C8 + (o & 31)] =
                    __float2bfloat16(acc[mf][nf][q] + bias);
            }
}

// -------------------- K2: v projection (MFMA) -> vb [B][C][N] ---------------
// D[c][n] = sum_d wv[c][d] * xbT[n][d].  M=256, N=64, K=256
__global__ __launch_bounds__(256) void v_kernel(
    const __hip_bfloat16* __restrict__ xbT, const __hip_bfloat16* __restrict__ wvb,
    const float* __restrict__ bv, __hip_bfloat16* __restrict__ vb)
{
    const int b = blockIdx.y, n0 = blockIdx.x * 64;
    const int tid = threadIdx.x;
    const int w = tid >> 6, l = tid & 63, g = l >> 4, li = l & 15;

    __shared__ __align__(16) char smem[40960];
    __hip_bfloat16* Ap = (__hip_bfloat16*)smem;            // wv rows (c), 32KB
    __hip_bfloat16* Bp = (__hip_bfloat16*)(smem + 32768);  // xbT rows (n), 8KB
    __hip_bfloat16* vt = (__hip_bfloat16*)smem;            // [256][72] reuse

    f32x4 acc[4][4];
    #pragma unroll
    for (int mf = 0; mf < 4; ++mf)
        #pragma unroll
        for (int nf = 0; nf < 4; ++nf) acc[mf][nf] = (f32x4){0.f,0.f,0.f,0.f};

    const __hip_bfloat16* bsrc = xbT + ((size_t)b*NP + n0)*CH;
    for (int kt4 = 0; kt4 < 4; ++kt4) {
        stage_panel64(wvb, CH, kt4*64, Ap, 256, w, l);
        stage_panel64(bsrc, CH, kt4*64, Bp, 64, w, l);
        __syncthreads();
        #pragma unroll
        for (int ks = 0; ks < 2; ++ks) {
            bf16x8 af[4], bf[4];
            #pragma unroll
            for (int mf = 0; mf < 4; ++mf) af[mf] = frag64(Ap, w*64 + mf*16 + li, ks*4 + g);
            #pragma unroll
            for (int nf = 0; nf < 4; ++nf) bf[nf] = frag64(Bp, nf*16 + li, ks*4 + g);
            #pragma unroll
            for (int mf = 0; mf < 4; ++mf)
                #pragma unroll
                for (int nf = 0; nf < 4; ++nf)
                    acc[mf][nf] = MFMA16(af[mf], bf[nf], acc[mf][nf]);
        }
        __syncthreads();
    }
    // transpose through LDS for coalesced [c][n] stores
    #pragma unroll
    for (int mf = 0; mf < 4; ++mf)
        #pragma unroll
        for (int nf = 0; nf < 4; ++nf)
            #pragma unroll
            for (int q = 0; q < 4; ++q) {
                int c = w*64 + mf*16 + g*4 + q;
                int n = nf*16 + li;
                vt[c*72 + n] = __float2bfloat16(acc[mf][nf][q] + bv[c]);
            }
    __syncthreads();
    for (int S = tid; S < 2048; S += 256) {
        int c = S >> 3, s = S & 7;
        bf16x8 v = *(const bf16x8*)((const char*)vt + c*144 + s*16);
        *(bf16x8*)(vb + ((size_t)b*CH + c)*NP + n0 + s*8) = v;
    }
}

// -------------------- K3: CAM energy partials (MFMA) ------------------------
// E_part[b][kp][r][c] = sum_{n in kp-slice} x[r][n] x[c][n]
__global__ __launch_bounds__(256) void energy_kernel(
    const float* __restrict__ x, float* __restrict__ E_part)
{
    const int rh = blockIdx.x, kp = blockIdx.y, b = blockIdx.z;
    const int tid = threadIdx.x;
    const int w = tid >> 6, l = tid & 63, g = l >> 4, li = l & 15;

    __shared__ __align__(16) __hip_bfloat16 P[256*64];   // 32KB shared A/B panel

    f32x4 acc[16];
    #pragma unroll
    for (int nf = 0; nf < 16; ++nf) acc[nf] = (f32x4){0.f,0.f,0.f,0.f};

    const float* xp = x + (size_t)b*CH*NP;
    for (int kt4 = 0; kt4 < 16; ++kt4) {
        int k0 = kp*1024 + kt4*64;
        stage_panel64_f32(xp, NP, k0, P, 256, tid);
        __syncthreads();
        #pragma unroll
        for (int ks = 0; ks < 2; ++ks) {
            bf16x8 af = frag64(P, rh*64 + w*16 + li, ks*4 + g);
            #pragma unroll
            for (int nf = 0; nf < 16; ++nf) {
                bf16x8 bf = frag64(P, nf*16 + li, ks*4 + g);
                acc[nf] = MFMA16(af, bf, acc[nf]);
            }
        }
        __syncthreads();
    }
    #pragma unroll
    for (int nf = 0; nf < 16; ++nf)
        #pragma unroll
        for (int q = 0; q < 4; ++q) {
            int r = rh*64 + w*16 + g*4 + q;
            int c = nf*16 + li;
            E_part[(((size_t)b*4 + kp)*CH + r)*CH + c] = acc[nf][q];
        }
}

// -------------------- K4: softmax over C (fused partial reduce) -> bf16 -----
__global__ __launch_bounds__(256) void cam_softmax(
    const float* __restrict__ E_part, __hip_bfloat16* __restrict__ attnb)
{
    int b = blockIdx.y, r = blockIdx.x;
    int tid = threadIdx.x;
    int lane = tid & 63, wid = tid >> 6;
    const float* base = E_part + ((size_t)b*4*CH + r)*CH + tid;
    float e = base[0] + base[CH*CH] + base[2*CH*CH] + base[3*CH*CH];

    __shared__ float redm[4], reds[4];
    float m = e;
    #pragma unroll
    for (int off = 32; off >= 1; off >>= 1) m = fmaxf(m, __shfl_xor(m, off));
    if (lane == 0) redm[wid] = m;
    __syncthreads();
    m = fmaxf(fmaxf(redm[0], redm[1]), fmaxf(redm[2], redm[3]));

    float p = __expf(e - m);
    float s = p;
    #pragma unroll
    for (int off = 32; off >= 1; off >>= 1) s += __shfl_xor(s, off);
    if (lane == 0) reds[wid] = s;
    __syncthreads();
    s = reds[0] + reds[1] + reds[2] + reds[3];
    attnb[((size_t)b*CH + r)*CH + tid] = __float2bfloat16(p / s);
}

// -------------------- K5: out = gamma*(A@X) + x (MFMA) ----------------------
// D[c][n] = sum_d attn[c][d] * xbT[n][d].  M=256, N=64, K=256
__global__ __launch_bounds__(256) void apply_kernel(
    const __hip_bfloat16* __restrict__ attnb, const __hip_bfloat16* __restrict__ xbT,
    const float* __restrict__ x, const float* __restrict__ gamma,
    float* __restrict__ out)
{
    const int b = blockIdx.y, n0 = blockIdx.x * 64;
    const int tid = threadIdx.x;
    const int w = tid >> 6, l = tid & 63, g = l >> 4, li = l & 15;

    __shared__ __align__(16) __hip_bfloat16 Ap[256*64];   // attn rows (c) 32KB
    __shared__ __align__(16) __hip_bfloat16 Bp[64*64];    // xbT rows (n)  8KB

    f32x4 acc[4][4];
    #pragma unroll
    for (int mf = 0; mf < 4; ++mf)
        #pragma unroll
        for (int nf = 0; nf < 4; ++nf) acc[mf][nf] = (f32x4){0.f,0.f,0.f,0.f};

    const __hip_bfloat16* asrc = attnb + (size_t)b*CH*CH;
    const __hip_bfloat16* bsrc = xbT + ((size_t)b*NP + n0)*CH;
    for (int kt4 = 0; kt4 < 4; ++kt4) {
        stage_panel64(asrc, CH, kt4*64, Ap, 256, w, l);
        stage_panel64(bsrc, CH, kt4*64, Bp, 64, w, l);
        __syncthreads();
        #pragma unroll
        for (int ks = 0; ks < 2; ++ks) {
            bf16x8 af[4], bf[4];
            #pragma unroll
            for (int mf = 0; mf < 4; ++mf) af[mf] = frag64(Ap, w*64 + mf*16 + li, ks*4 + g);
            #pragma unroll
            for (int nf = 0; nf < 4; ++nf) bf[nf] = frag64(Bp, nf*16 + li, ks*4 + g);
            #pragma unroll
            for (int mf = 0; mf < 4; ++mf)
                #pragma unroll
                for (int nf = 0; nf < 4; ++nf)
                    acc[mf][nf] = MFMA16(af[mf], bf[nf], acc[mf][nf]);
        }
        __syncthreads();
    }
    float g0 = gamma[0];
    #pragma unroll
    for (int mf = 0; mf < 4; ++mf)
        #pragma unroll
        for (int nf = 0; nf < 4; ++nf)
            #pragma unroll
            for (int q = 0; q < 4; ++q) {
                int c = w*64 + mf*16 + g*4 + q;
                int n = n0 + nf*16 + li;
                size_t idx = ((size_t)b*CH + c)*NP + n;
                out[idx] = g0*acc[mf][nf][q] + x[idx];
            }
}

// -------------------- K6: PAM flash (MFMA bf16, unnormalized exp) -----------
__global__ __launch_bounds__(256) void pam_flash(
    const __hip_bfloat16* __restrict__ qg,   // [B][N][32]
    const __hip_bfloat16* __restrict__ kg,   // [B][N][32]
    const __hip_bfloat16* __restrict__ vg,   // [B][C][N]
    float* __restrict__ out)
{
    const int b  = blockIdx.y;
    const int i0 = blockIdx.x * 64;
    const int tid = threadIdx.x;
    const int w  = tid >> 6;
    const int l  = tid & 63;
    const int g  = l >> 4;
    const int li = l & 15;

    __shared__ __align__(16) __hip_bfloat16 qt[64*32];
    __shared__ __align__(16) __hip_bfloat16 kt[64*32];
    __shared__ __align__(16) __hip_bfloat16 vs[256*64];
    __shared__ __align__(16) __hip_bfloat16 ps[64*72];
    __shared__ float lsh[4][64];

    {
        const char* src = (const char*)(qg + ((size_t)b*NP + i0)*C8) + (size_t)w*1024 + l*16;
        async_copy16(src, (char*)qt + w*1024);
    }
    __syncthreads();

    bf16x8 qf[4];
    #pragma unroll
    for (int t = 0; t < 4; ++t)
        qf[t] = *(const bf16x8*)((const char*)qt + (t*16 + li)*64 + g*16);

    f32x4 acc[4][4];
    #pragma unroll
    for (int t = 0; t < 4; ++t)
        #pragma unroll
        for (int ct = 0; ct < 4; ++ct)
            acc[t][ct] = (f32x4){0.f, 0.f, 0.f, 0.f};
    float lacc[4] = {0.f, 0.f, 0.f, 0.f};

    for (int j0 = 0; j0 < NP; j0 += 64) {
        {
            const char* src = (const char*)(kg + ((size_t)b*NP + j0)*C8) + (size_t)w*1024 + l*16;
            async_copy16(src, (char*)kt + w*1024);
        }
        #pragma unroll
        for (int it = 0; it < 8; ++it) {
            int S16 = w*512 + it*64 + l;
            int c   = S16 >> 3;
            int jb  = (S16 & 7) ^ (c & 7);
            const char* src = (const char*)vg +
                ((size_t)(b*CH + c)*NP + j0 + jb*8)*2;
            async_copy16(src, (char*)vs + w*8192 + it*1024);
        }
        __syncthreads();

        bf16x8 ka = *(const bf16x8*)((const char*)kt + (w*16 + li)*64 + g*16);
        f32x4 st[4];
        #pragma unroll
        for (int t = 0; t < 4; ++t) {
            f32x4 z = (f32x4){0.f, 0.f, 0.f, 0.f};
            st[t] = MFMA16(ka, qf[t], z);
        }
        #pragma unroll
        for (int t = 0; t < 4; ++t) {
            float p0 = __expf(st[t][0]);
            float p1 = __expf(st[t][1]);
            float p2 = __expf(st[t][2]);
            float p3 = __expf(st[t][3]);
            lacc[t] += (p0 + p1) + (p2 + p3);
            *(unsigned long long*)((char*)ps + (t*16 + li)*144 + (w*16 + g*4)*2)
                = pack4bf(p0, p1, p2, p3);
        }
        __syncthreads();

        #pragma unroll
        for (int ks = 0; ks < 2; ++ks) {
            bf16x8 ap[4];
            #pragma unroll
            for (int t = 0; t < 4; ++t)
                ap[t] = *(const bf16x8*)((const char*)ps + (t*16 + li)*144 + ks*64 + g*16);
            #pragma unroll
            for (int ct = 0; ct < 4; ++ct) {
                int c = w*64 + ct*16 + li;
                bf16x8 bv = *(const bf16x8*)((const char*)vs + c*128 +
                                (((ks*4 + g) ^ (c & 7)) << 4));
                #pragma unroll
                for (int t = 0; t < 4; ++t)
                    acc[t][ct] = MFMA16(ap[t], bv, acc[t][ct]);
            }
        }
        __syncthreads();
    }

    #pragma unroll
    for (int t = 0; t < 4; ++t) {
        float v = lacc[t];
        v += __shfl_xor(v, 16);
        v += __shfl_xor(v, 32);
        lacc[t] = v;
    }
    if (g == 0) {
        #pragma unroll
        for (int t = 0; t < 4; ++t) lsh[w][t*16 + li] = lacc[t];
    }
    __syncthreads();

    #pragma unroll
    for (int t = 0; t < 4; ++t) {
        float linv[4];
        #pragma unroll
        for (int r = 0; r < 4; ++r) {
            int il = t*16 + g*4 + r;
            linv[r] = 1.0f / (lsh[0][il] + lsh[1][il] + lsh[2][il] + lsh[3][il]);
        }
        #pragma unroll
        for (int ct = 0; ct < 4; ++ct) {
            int c = w*64 + ct*16 + li;
            size_t base = ((size_t)b*CH + c)*NP + i0 + t*16 + g*4;
            float4 o = *(float4*)(out + base);
            o.x += acc[t][ct][0]*linv[0];
            o.y += acc[t][ct][1]*linv[1];
            o.z += acc[t][ct][2]*linv[2];
            o.w += acc[t][ct][3]*linv[3];
            *(float4*)(out + base) = o;
        }
    }
}

// ---------------------------------------------------------------------------
extern "C" void kernel_launch(void* const* d_in, const int* in_sizes, int n_in,
                              void* d_out, int out_size, void* d_ws, size_t ws_size,
                              hipStream_t stream)
{
    const float* x     = (const float*)d_in[0];
    const float* gamma = (const float*)d_in[1];
    const float* wq    = (const float*)d_in[2];
    const float* bq    = (const float*)d_in[3];
    const float* wk    = (const float*)d_in[4];
    const float* bk    = (const float*)d_in[5];
    const float* wv    = (const float*)d_in[6];
    const float* bv    = (const float*)d_in[7];
    float* out = (float*)d_out;

    char* ws = (char*)d_ws;
    __hip_bfloat16* xbT   = (__hip_bfloat16*)ws;                 ws += (size_t)BB*NP*CH*2;  // 16MB
    __hip_bfloat16* qtb   = (__hip_bfloat16*)ws;                 ws += (size_t)BB*NP*C8*2;  // 2MB
    __hip_bfloat16* ktb   = (__hip_bfloat16*)ws;                 ws += (size_t)BB*NP*C8*2;  // 2MB
    __hip_bfloat16* vbb   = (__hip_bfloat16*)ws;                 ws += (size_t)BB*CH*NP*2;  // 16MB
    __hip_bfloat16* wqkb  = (__hip_bfloat16*)ws;                 ws += 64*CH*2;
    __hip_bfloat16* wvb   = (__hip_bfloat16*)ws;                 ws += CH*CH*2;
    float*          Epart = (float*)ws;                          ws += (size_t)BB*4*CH*CH*4; // 8MB
    __hip_bfloat16* attnb = (__hip_bfloat16*)ws;                 ws += (size_t)BB*CH*CH*2;   // 1MB

    convert_w   <<<dim3(320),        256, 0, stream>>>(wq, wk, wv, wqkb, wvb);
    convert_T   <<<dim3(64, 4, BB),  256, 0, stream>>>(x, xbT);
    qk_kernel   <<<dim3(32, BB),     256, 0, stream>>>(xbT, wqkb, bq, bk, qtb, ktb);
    v_kernel    <<<dim3(64, BB),     256, 0, stream>>>(xbT, wvb, bv, vbb);
    energy_kernel<<<dim3(4, 4, BB),  256, 0, stream>>>(x, Epart);
    cam_softmax <<<dim3(CH, BB),     256, 0, stream>>>(Epart, attnb);
    apply_kernel<<<dim3(64, BB),     256, 0, stream>>>(attnb, xbT, x, gamma, out);
    pam_flash   <<<dim3(NP/64, BB),  256, 0, stream>>>(qtb, ktb, vbb, out);
}

// Round 4
// 228.176 us; speedup vs baseline: 27.1044x; 1.0667x over previous
//
#include <hip/hip_runtime.h>
#include <hip/hip_bf16.h>

#define BB 8
#define CH 256
#define C8 32
#define NP 4096   // 64*64

typedef __attribute__((ext_vector_type(8))) short bf16x8;
typedef __attribute__((ext_vector_type(4))) float f32x4;

#define MFMA16(a, b, c) __builtin_amdgcn_mfma_f32_16x16x32_bf16(a, b, c, 0, 0, 0)
#define SBAR() __builtin_amdgcn_sched_barrier(0)

#if __has_builtin(__builtin_amdgcn_exp2f)
#define EXP2(x) __builtin_amdgcn_exp2f(x)
#else
#define EXP2(x) exp2f(x)
#endif

#define LOG2E 1.44269504088896340736f

__device__ __forceinline__ void async_copy16(const void* src, void* dst_lds) {
    __builtin_amdgcn_global_load_lds(
        (const __attribute__((address_space(1))) unsigned int*)src,
        (__attribute__((address_space(3))) unsigned int*)dst_lds, 16, 0, 0);
}

__device__ __forceinline__ unsigned long long pack4bf(float a, float b, float c, float d) {
    union { __hip_bfloat16 h[4]; unsigned long long u; } p;
    p.h[0] = __float2bfloat16(a);
    p.h[1] = __float2bfloat16(b);
    p.h[2] = __float2bfloat16(c);
    p.h[3] = __float2bfloat16(d);
    return p.u;
}

// Stage a [nrows][64] bf16 LDS panel (128B rows, XOR-swizzled: data k-chunk t
// of row r lives at slot t^(r&7)) from row-major bf16 global.
__device__ __forceinline__ void stage_panel64(
    const __hip_bfloat16* __restrict__ src, int rowStride, int k0,
    __hip_bfloat16* lds, int nrows, int w, int l)
{
    const int nslots = nrows * 8;
    for (int S0 = w*64; S0 < nslots; S0 += 256) {
        int S = S0 + l;
        int r = S >> 3, s = S & 7;
        int jb = s ^ (r & 7);
        async_copy16(src + (size_t)r*rowStride + k0 + jb*8,
                     (char*)lds + (size_t)S0*16);
    }
}

// Same panel layout but from fp32 global, converted through registers.
__device__ __forceinline__ void stage_panel64_f32(
    const float* __restrict__ src, int rowStride, int k0,
    __hip_bfloat16* lds, int nrows, int tid)
{
    const int nslots = nrows * 8;
    for (int S = tid; S < nslots; S += 256) {
        int r = S >> 3, s = S & 7;
        int jb = s ^ (r & 7);
        const float* p = src + (size_t)r*rowStride + k0 + jb*8;
        float4 a = *(const float4*)p;
        float4 b = *(const float4*)(p + 4);
        union { __hip_bfloat16 h[8]; bf16x8 v; } u;
        u.h[0] = __float2bfloat16(a.x); u.h[1] = __float2bfloat16(a.y);
        u.h[2] = __float2bfloat16(a.z); u.h[3] = __float2bfloat16(a.w);
        u.h[4] = __float2bfloat16(b.x); u.h[5] = __float2bfloat16(b.y);
        u.h[6] = __float2bfloat16(b.z); u.h[7] = __float2bfloat16(b.w);
        *(bf16x8*)((char*)lds + (size_t)S*16) = u.v;
    }
}

__device__ __forceinline__ bf16x8 frag64(const __hip_bfloat16* lds, int r, int t) {
    return *(const bf16x8*)((const char*)lds + r*128 + ((t ^ (r & 7)) << 4));
}

// -------------------- K0a: weights -> bf16 ----------------------------------
__global__ __launch_bounds__(256) void convert_w(
    const float* __restrict__ wq, const float* __restrict__ wk,
    const float* __restrict__ wv,
    __hip_bfloat16* __restrict__ wqkb, __hip_bfloat16* __restrict__ wvb)
{
    int id = blockIdx.x * 256 + threadIdx.x;
    if (id < 64*256) {
        float v = (id < 32*256) ? wq[id] : wk[id - 32*256];
        wqkb[id] = __float2bfloat16(v);
    } else {
        int j = id - 64*256;
        wvb[j] = __float2bfloat16(wv[j]);
    }
}

// -------------------- K0b: x -> xbT [B][N][C] bf16 (transpose) --------------
__global__ __launch_bounds__(256) void convert_T(
    const float* __restrict__ x, __hip_bfloat16* __restrict__ xbT)
{
    int b = blockIdx.z, c0 = blockIdx.y * 64, n0 = blockIdx.x * 64;
    __shared__ float t[64][65];
    int tid = threadIdx.x;
    int nn = tid & 63, ch = tid >> 6;
    const float* xp = x + (size_t)b*CH*NP + (size_t)c0*NP + n0;
    #pragma unroll
    for (int u = 0; u < 16; ++u)
        t[ch + u*4][nn] = xp[(size_t)(ch + u*4)*NP + nn];
    __syncthreads();
    int n = tid >> 2, seg = tid & 3;
    union { __hip_bfloat16 h[16]; bf16x8 v[2]; } u16;
    #pragma unroll
    for (int u = 0; u < 16; ++u)
        u16.h[u] = __float2bfloat16(t[seg*16 + u][n]);
    __hip_bfloat16* dst = xbT + ((size_t)b*NP + n0 + n)*CH + c0 + seg*16;
    *(bf16x8*)dst = u16.v[0];
    *(bf16x8*)(dst + 8) = u16.v[1];
}

// -------------------- K1: q,k projections (MFMA) ----------------------------
// D[n][o] = sum_d xbT[n][d] * wqk[o][d];  o<32 -> q (scaled by log2e), else k.
__global__ __launch_bounds__(256) void qk_kernel(
    const __hip_bfloat16* __restrict__ xbT, const __hip_bfloat16* __restrict__ wqkb,
    const float* __restrict__ bq, const float* __restrict__ bk,
    __hip_bfloat16* __restrict__ qt, __hip_bfloat16* __restrict__ kt)
{
    const int b = blockIdx.y, n0 = blockIdx.x * 128;
    const int tid = threadIdx.x;
    const int w = tid >> 6, l = tid & 63, g = l >> 4, li = l & 15;

    __shared__ __align__(16) __hip_bfloat16 Ap[128*64];
    __shared__ __align__(16) __hip_bfloat16 Bp[64*64];

    f32x4 acc[2][4];
    #pragma unroll
    for (int mf = 0; mf < 2; ++mf)
        #pragma unroll
        for (int nf = 0; nf < 4; ++nf) acc[mf][nf] = (f32x4){0.f,0.f,0.f,0.f};

    const __hip_bfloat16* asrc = xbT + ((size_t)b*NP + n0)*CH;
    for (int kt4 = 0; kt4 < 4; ++kt4) {
        stage_panel64(asrc, CH, kt4*64, Ap, 128, w, l);
        stage_panel64(wqkb, CH, kt4*64, Bp, 64, w, l);
        __syncthreads();
        #pragma unroll
        for (int ks = 0; ks < 2; ++ks) {
            bf16x8 af[2], bf[4];
            #pragma unroll
            for (int mf = 0; mf < 2; ++mf) af[mf] = frag64(Ap, w*32 + mf*16 + li, ks*4 + g);
            #pragma unroll
            for (int nf = 0; nf < 4; ++nf) bf[nf] = frag64(Bp, nf*16 + li, ks*4 + g);
            #pragma unroll
            for (int mf = 0; mf < 2; ++mf)
                #pragma unroll
                for (int nf = 0; nf < 4; ++nf)
                    acc[mf][nf] = MFMA16(af[mf], bf[nf], acc[mf][nf]);
        }
        __syncthreads();
    }
    #pragma unroll
    for (int mf = 0; mf < 2; ++mf)
        #pragma unroll
        for (int nf = 0; nf < 4; ++nf)
            #pragma unroll
            for (int q = 0; q < 4; ++q) {
                int n = n0 + w*32 + mf*16 + g*4 + q;
                int o = nf*16 + li;
                float bias = (o < 32) ? bq[o] : bk[o - 32];
                float scl  = (o < 32) ? LOG2E : 1.0f;
                __hip_bfloat16* dst = (o < 32) ? qt : kt;
                dst[((size_t)b*NP + n)*C8 + (o & 31)] =
                    __float2bfloat16((acc[mf][nf][q] + bias) * scl);
            }
}

// -------------------- K2: v projection (MFMA) -> vb [B][C][N] ---------------
__global__ __launch_bounds__(256) void v_kernel(
    const __hip_bfloat16* __restrict__ xbT, const __hip_bfloat16* __restrict__ wvb,
    const float* __restrict__ bv, __hip_bfloat16* __restrict__ vb)
{
    const int b = blockIdx.y, n0 = blockIdx.x * 64;
    const int tid = threadIdx.x;
    const int w = tid >> 6, l = tid & 63, g = l >> 4, li = l & 15;

    __shared__ __align__(16) char smem[40960];
    __hip_bfloat16* Ap = (__hip_bfloat16*)smem;
    __hip_bfloat16* Bp = (__hip_bfloat16*)(smem + 32768);
    __hip_bfloat16* vt = (__hip_bfloat16*)smem;

    f32x4 acc[4][4];
    #pragma unroll
    for (int mf = 0; mf < 4; ++mf)
        #pragma unroll
        for (int nf = 0; nf < 4; ++nf) acc[mf][nf] = (f32x4){0.f,0.f,0.f,0.f};

    const __hip_bfloat16* bsrc = xbT + ((size_t)b*NP + n0)*CH;
    for (int kt4 = 0; kt4 < 4; ++kt4) {
        stage_panel64(wvb, CH, kt4*64, Ap, 256, w, l);
        stage_panel64(bsrc, CH, kt4*64, Bp, 64, w, l);
        __syncthreads();
        #pragma unroll
        for (int ks = 0; ks < 2; ++ks) {
            bf16x8 af[4], bf[4];
            #pragma unroll
            for (int mf = 0; mf < 4; ++mf) af[mf] = frag64(Ap, w*64 + mf*16 + li, ks*4 + g);
            #pragma unroll
            for (int nf = 0; nf < 4; ++nf) bf[nf] = frag64(Bp, nf*16 + li, ks*4 + g);
            #pragma unroll
            for (int mf = 0; mf < 4; ++mf)
                #pragma unroll
                for (int nf = 0; nf < 4; ++nf)
                    acc[mf][nf] = MFMA16(af[mf], bf[nf], acc[mf][nf]);
        }
        __syncthreads();
    }
    #pragma unroll
    for (int mf = 0; mf < 4; ++mf)
        #pragma unroll
        for (int nf = 0; nf < 4; ++nf)
            #pragma unroll
            for (int q = 0; q < 4; ++q) {
                int c = w*64 + mf*16 + g*4 + q;
                int n = nf*16 + li;
                vt[c*72 + n] = __float2bfloat16(acc[mf][nf][q] + bv[c]);
            }
    __syncthreads();
    for (int S = tid; S < 2048; S += 256) {
        int c = S >> 3, s = S & 7;
        bf16x8 v = *(const bf16x8*)((const char*)vt + c*144 + s*16);
        *(bf16x8*)(vb + ((size_t)b*CH + c)*NP + n0 + s*8) = v;
    }
}

// -------------------- K3: CAM energy partials (MFMA) ------------------------
__global__ __launch_bounds__(256) void energy_kernel(
    const float* __restrict__ x, float* __restrict__ E_part)
{
    const int rh = blockIdx.x, kp = blockIdx.y, b = blockIdx.z;
    const int tid = threadIdx.x;
    const int w = tid >> 6, l = tid & 63, g = l >> 4, li = l & 15;

    __shared__ __align__(16) __hip_bfloat16 P[256*64];

    f32x4 acc[16];
    #pragma unroll
    for (int nf = 0; nf < 16; ++nf) acc[nf] = (f32x4){0.f,0.f,0.f,0.f};

    const float* xp = x + (size_t)b*CH*NP;
    for (int kt4 = 0; kt4 < 16; ++kt4) {
        int k0 = kp*1024 + kt4*64;
        stage_panel64_f32(xp, NP, k0, P, 256, tid);
        __syncthreads();
        #pragma unroll
        for (int ks = 0; ks < 2; ++ks) {
            bf16x8 af = frag64(P, rh*64 + w*16 + li, ks*4 + g);
            #pragma unroll
            for (int nf = 0; nf < 16; ++nf) {
                bf16x8 bf = frag64(P, nf*16 + li, ks*4 + g);
                acc[nf] = MFMA16(af, bf, acc[nf]);
            }
        }
        __syncthreads();
    }
    #pragma unroll
    for (int nf = 0; nf < 16; ++nf)
        #pragma unroll
        for (int q = 0; q < 4; ++q) {
            int r = rh*64 + w*16 + g*4 + q;
            int c = nf*16 + li;
            E_part[(((size_t)b*4 + kp)*CH + r)*CH + c] = acc[nf][q];
        }
}

// -------------------- K4: softmax over C (fused partial reduce) -> bf16 -----
__global__ __launch_bounds__(256) void cam_softmax(
    const float* __restrict__ E_part, __hip_bfloat16* __restrict__ attnb)
{
    int b = blockIdx.y, r = blockIdx.x;
    int tid = threadIdx.x;
    int lane = tid & 63, wid = tid >> 6;
    const float* base = E_part + ((size_t)b*4*CH + r)*CH + tid;
    float e = base[0] + base[CH*CH] + base[2*CH*CH] + base[3*CH*CH];

    __shared__ float redm[4], reds[4];
    float m = e;
    #pragma unroll
    for (int off = 32; off >= 1; off >>= 1) m = fmaxf(m, __shfl_xor(m, off));
    if (lane == 0) redm[wid] = m;
    __syncthreads();
    m = fmaxf(fmaxf(redm[0], redm[1]), fmaxf(redm[2], redm[3]));

    float p = __expf(e - m);
    float s = p;
    #pragma unroll
    for (int off = 32; off >= 1; off >>= 1) s += __shfl_xor(s, off);
    if (lane == 0) reds[wid] = s;
    __syncthreads();
    s = reds[0] + reds[1] + reds[2] + reds[3];
    attnb[((size_t)b*CH + r)*CH + tid] = __float2bfloat16(p / s);
}

// -------------------- K5: out = gamma*(A@X) + x (MFMA) ----------------------
__global__ __launch_bounds__(256) void apply_kernel(
    const __hip_bfloat16* __restrict__ attnb, const __hip_bfloat16* __restrict__ xbT,
    const float* __restrict__ x, const float* __restrict__ gamma,
    float* __restrict__ out)
{
    const int b = blockIdx.y, n0 = blockIdx.x * 64;
    const int tid = threadIdx.x;
    const int w = tid >> 6, l = tid & 63, g = l >> 4, li = l & 15;

    __shared__ __align__(16) __hip_bfloat16 Ap[256*64];
    __shared__ __align__(16) __hip_bfloat16 Bp[64*64];

    f32x4 acc[4][4];
    #pragma unroll
    for (int mf = 0; mf < 4; ++mf)
        #pragma unroll
        for (int nf = 0; nf < 4; ++nf) acc[mf][nf] = (f32x4){0.f,0.f,0.f,0.f};

    const __hip_bfloat16* asrc = attnb + (size_t)b*CH*CH;
    const __hip_bfloat16* bsrc = xbT + ((size_t)b*NP + n0)*CH;
    for (int kt4 = 0; kt4 < 4; ++kt4) {
        stage_panel64(asrc, CH, kt4*64, Ap, 256, w, l);
        stage_panel64(bsrc, CH, kt4*64, Bp, 64, w, l);
        __syncthreads();
        #pragma unroll
        for (int ks = 0; ks < 2; ++ks) {
            bf16x8 af[4], bf[4];
            #pragma unroll
            for (int mf = 0; mf < 4; ++mf) af[mf] = frag64(Ap, w*64 + mf*16 + li, ks*4 + g);
            #pragma unroll
            for (int nf = 0; nf < 4; ++nf) bf[nf] = frag64(Bp, nf*16 + li, ks*4 + g);
            #pragma unroll
            for (int mf = 0; mf < 4; ++mf)
                #pragma unroll
                for (int nf = 0; nf < 4; ++nf)
                    acc[mf][nf] = MFMA16(af[mf], bf[nf], acc[mf][nf]);
        }
        __syncthreads();
    }
    float g0 = gamma[0];
    #pragma unroll
    for (int mf = 0; mf < 4; ++mf)
        #pragma unroll
        for (int nf = 0; nf < 4; ++nf)
            #pragma unroll
            for (int q = 0; q < 4; ++q) {
                int c = w*64 + mf*16 + g*4 + q;
                int n = n0 + nf*16 + li;
                size_t idx = ((size_t)b*CH + c)*NP + n;
                out[idx] = g0*acc[mf][nf][q] + x[idx];
            }
}

// -------------------- K6: PAM flash v3 (pipelined, wave-private staging) ----
// q pre-scaled by log2e; p = exp2(s); out[b][c][i] += (sum_j p*v[c][j])/(sum_j p)
__global__ __launch_bounds__(256) void pam_flash(
    const __hip_bfloat16* __restrict__ qg,   // [B][N][32] (pre-scaled)
    const __hip_bfloat16* __restrict__ kg,   // [B][N][32]
    const __hip_bfloat16* __restrict__ vg,   // [B][C][N]
    float* __restrict__ out)
{
    const int b  = blockIdx.y;
    const int i0 = blockIdx.x * 64;
    const int tid = threadIdx.x;
    const int w  = tid >> 6;
    const int l  = tid & 63;
    const int g  = l >> 4;
    const int li = l & 15;

    __shared__ __align__(16) __hip_bfloat16 qt[64*32];       // 4KB
    __shared__ __align__(16) __hip_bfloat16 kt2[2][64*32];   // 8KB (dbuf)
    __shared__ __align__(16) __hip_bfloat16 vs[256*64];      // 32KB swizzled
    __shared__ __align__(16) __hip_bfloat16 ps[64*64];       // 8KB swizzled
    __shared__ float lsh[4][64];                             // 1KB

    // hoisted per-lane staging sources (wave-private rows)
    const char* qsrc  = (const char*)(qg + ((size_t)b*NP + i0)*C8) + w*1024 + l*16;
    const char* ksrc0 = (const char*)(kg + (size_t)b*NP*C8) + w*1024 + l*16;
    const char* vsrc[8];
    int vdst[8];
    #pragma unroll
    for (int it = 0; it < 8; ++it) {
        int S16 = w*512 + it*64 + l;
        int c   = S16 >> 3;
        int jb  = (S16 & 7) ^ (c & 7);
        vsrc[it] = (const char*)vg + ((size_t)(b*CH + c)*NP + jb*8)*2;
        vdst[it] = w*8192 + it*1024;
    }

    // prologue: qt + kt tile 0
    async_copy16(qsrc, (char*)qt + w*1024);
    async_copy16(ksrc0, (char*)kt2[0] + w*1024);
    __syncthreads();

    bf16x8 qf[4];
    #pragma unroll
    for (int t = 0; t < 4; ++t)
        qf[t] = *(const bf16x8*)((const char*)qt + (t*16 + li)*64 + g*16);

    f32x4 acc[4][4];
    #pragma unroll
    for (int t = 0; t < 4; ++t)
        #pragma unroll
        for (int ct = 0; ct < 4; ++ct)
            acc[t][ct] = (f32x4){0.f, 0.f, 0.f, 0.f};
    float lacc[4] = {0.f, 0.f, 0.f, 0.f};

    for (int jt = 0; jt < 64; ++jt) {
        const int cur = jt & 1;
        // ---- A: prefetch next K tile; stage this V tile (wave-private) ----
        if (jt < 63)
            async_copy16(ksrc0 + (size_t)(jt + 1)*4096, (char*)kt2[cur ^ 1] + w*1024);
        #pragma unroll
        for (int it = 0; it < 8; ++it)
            async_copy16(vsrc[it] + (size_t)jt*128, (char*)vs + vdst[it]);

        // ---- B: QK^T (kt2[cur] drained at prev D / prologue) + exp2 ----
        bf16x8 ka = *(const bf16x8*)((const char*)kt2[cur] + (w*16 + li)*64 + g*16);
        f32x4 st[4];
        #pragma unroll
        for (int t = 0; t < 4; ++t) {
            f32x4 z = (f32x4){0.f, 0.f, 0.f, 0.f};
            st[t] = MFMA16(ka, qf[t], z);
        }
        #pragma unroll
        for (int t = 0; t < 4; ++t) {
            float p0 = EXP2(st[t][0]);
            float p1 = EXP2(st[t][1]);
            float p2 = EXP2(st[t][2]);
            float p3 = EXP2(st[t][3]);
            lacc[t] += (p0 + p1) + (p2 + p3);
            // ps[i = t*16+li][j = w*16+g*4 .. +4], swizzled chunk = (2w+(g>>1)) ^ (li&7)
            *(unsigned long long*)((char*)ps + (t*16 + li)*128 +
                (((2*w + (g >> 1)) ^ (li & 7)) << 4) + ((g & 1) << 3))
                = pack4bf(p0, p1, p2, p3);
        }

        // ---- C: publish ps only (no vmcnt drain: staging loads keep flying) ----
        asm volatile("s_waitcnt lgkmcnt(0)" ::: "memory");
        SBAR();
        __builtin_amdgcn_s_barrier();
        SBAR();

        // ---- D: wait own staging loads, then PV ----
        asm volatile("s_waitcnt vmcnt(0)" ::: "memory");
        SBAR();
        #pragma unroll
        for (int ks = 0; ks < 2; ++ks) {
            bf16x8 ap[4];
            #pragma unroll
            for (int t = 0; t < 4; ++t)
                ap[t] = *(const bf16x8*)((const char*)ps + (t*16 + li)*128 +
                            (((ks*4 + g) ^ (li & 7)) << 4));
            #pragma unroll
            for (int ct = 0; ct < 4; ++ct) {
                int c = w*64 + ct*16 + li;
                bf16x8 bv = *(const bf16x8*)((const char*)vs + c*128 +
                                (((ks*4 + g) ^ (c & 7)) << 4));
                #pragma unroll
                for (int t = 0; t < 4; ++t)
                    acc[t][ct] = MFMA16(ap[t], bv, acc[t][ct]);
            }
        }

        // ---- E: free ps (vs/kt are wave-private) ----
        SBAR();
        __builtin_amdgcn_s_barrier();
        SBAR();
    }

    // ---- reduce l across lane groups then waves ----
    #pragma unroll
    for (int t = 0; t < 4; ++t) {
        float v = lacc[t];
        v += __shfl_xor(v, 16);
        v += __shfl_xor(v, 32);
        lacc[t] = v;
    }
    if (g == 0) {
        #pragma unroll
        for (int t = 0; t < 4; ++t) lsh[w][t*16 + li] = lacc[t];
    }
    __syncthreads();

    #pragma unroll
    for (int t = 0; t < 4; ++t) {
        float linv[4];
        #pragma unroll
        for (int r = 0; r < 4; ++r) {
            int il = t*16 + g*4 + r;
            linv[r] = 1.0f / (lsh[0][il] + lsh[1][il] + lsh[2][il] + lsh[3][il]);
        }
        #pragma unroll
        for (int ct = 0; ct < 4; ++ct) {
            int c = w*64 + ct*16 + li;
            size_t base = ((size_t)b*CH + c)*NP + i0 + t*16 + g*4;
            float4 o = *(float4*)(out + base);
            o.x += acc[t][ct][0]*linv[0];
            o.y += acc[t][ct][1]*linv[1];
            o.z += acc[t][ct][2]*linv[2];
            o.w += acc[t][ct][3]*linv[3];
            *(float4*)(out + base) = o;
        }
    }
}

// ---------------------------------------------------------------------------
extern "C" void kernel_launch(void* const* d_in, const int* in_sizes, int n_in,
                              void* d_out, int out_size, void* d_ws, size_t ws_size,
                              hipStream_t stream)
{
    const float* x     = (const float*)d_in[0];
    const float* gamma = (const float*)d_in[1];
    const float* wq    = (const float*)d_in[2];
    const float* bq    = (const float*)d_in[3];
    const float* wk    = (const float*)d_in[4];
    const float* bk    = (const float*)d_in[5];
    const float* wv    = (const float*)d_in[6];
    const float* bv    = (const float*)d_in[7];
    float* out = (float*)d_out;

    char* ws = (char*)d_ws;
    __hip_bfloat16* xbT   = (__hip_bfloat16*)ws;                 ws += (size_t)BB*NP*CH*2;
    __hip_bfloat16* qtb   = (__hip_bfloat16*)ws;                 ws += (size_t)BB*NP*C8*2;
    __hip_bfloat16* ktb   = (__hip_bfloat16*)ws;                 ws += (size_t)BB*NP*C8*2;
    __hip_bfloat16* vbb   = (__hip_bfloat16*)ws;                 ws += (size_t)BB*CH*NP*2;
    __hip_bfloat16* wqkb  = (__hip_bfloat16*)ws;                 ws += 64*CH*2;
    __hip_bfloat16* wvb   = (__hip_bfloat16*)ws;                 ws += CH*CH*2;
    float*          Epart = (float*)ws;                          ws += (size_t)BB*4*CH*CH*4;
    __hip_bfloat16* attnb = (__hip_bfloat16*)ws;                 ws += (size_t)BB*CH*CH*2;

    convert_w   <<<dim3(320),        256, 0, stream>>>(wq, wk, wv, wqkb, wvb);
    convert_T   <<<dim3(64, 4, BB),  256, 0, stream>>>(x, xbT);
    qk_kernel   <<<dim3(32, BB),     256, 0, stream>>>(xbT, wqkb, bq, bk, qtb, ktb);
    v_kernel    <<<dim3(64, BB),     256, 0, stream>>>(xbT, wvb, bv, vbb);
    energy_kernel<<<dim3(4, 4, BB),  256, 0, stream>>>(x, Epart);
    cam_softmax <<<dim3(CH, BB),     256, 0, stream>>>(Epart, attnb);
    apply_kernel<<<dim3(64, BB),     256, 0, stream>>>(attnb, xbT, x, gamma, out);
    pam_flash   <<<dim3(NP/64, BB),  256, 0, stream>>>(qtb, ktb, vbb, out);
}